// Round 5
// baseline (710.764 us; speedup 1.0000x reference)
//
#include <hip/hip_runtime.h>

#define BB 16
#define MM 32
#define LH 128
#define NSTEPS 15          // K-1
#define SSTR 136
#define NBLK 256           // 2 rows per block
#define FSTR 32            // flag stride in ints (128 B apart)

typedef __bf16  bf16x8  __attribute__((ext_vector_type(8)));
typedef float   floatx4 __attribute__((ext_vector_type(4)));

__device__ __forceinline__ float sigm(float x){ return 1.f/(1.f+__expf(-x)); }
__device__ __forceinline__ float tanh_f(float x){ return 1.f - 2.f/(__expf(2.f*x)+1.f); }

__device__ __forceinline__ unsigned short f2bf(float x){
  union { float f; unsigned u; } v; v.f = x;
  unsigned r = v.u + 0x7FFFu + ((v.u >> 16) & 1u);   // RNE
  return (unsigned short)(r >> 16);
}
__device__ __forceinline__ float bf2f(unsigned short u){
  union { unsigned u; float f; } v; v.u = ((unsigned)u) << 16;
  return v.f;
}

// poison-safe spin: 0xAAAAAAAA reads as "far behind" under signed diff
__device__ __forceinline__ void wait_flag(int* f, int target){
  while ((int)(__hip_atomic_load(f, __ATOMIC_ACQUIRE, __HIP_MEMORY_SCOPE_AGENT) - target) < 0){
    __builtin_amdgcn_s_sleep(1);
  }
}
__device__ __forceinline__ void set_flag(int* f, int v){
  __threadfence();   // agent-scope release: L2 writeback so other XCDs see our data
  __hip_atomic_store(f, v, __ATOMIC_RELEASE, __HIP_MEMORY_SCOPE_AGENT);
}

__global__ __launch_bounds__(256, 1) void k_mega(
    const float* __restrict__ mp,   const float* __restrict__ gl,
    const float* __restrict__ W_hid,const float* __restrict__ b_hid,
    const float* __restrict__ W_h0, const float* __restrict__ b_h0,
    const float* __restrict__ W_c0, const float* __restrict__ b_c0,
    const float* __restrict__ Wf,   const float* __restrict__ bfs,
    const float* __restrict__ wih,  const float* __restrict__ bih,
    const float* __restrict__ Whh,  const float* __restrict__ bhh,
    const float* __restrict__ wpol,
    unsigned short* __restrict__ hA, unsigned short* __restrict__ hB,
    unsigned short* __restrict__ hidb,
    unsigned short* __restrict__ wc0, unsigned short* __restrict__ wc1,
    unsigned short* __restrict__ whhf, float* __restrict__ bsum,
    int* __restrict__ flags, float* __restrict__ out)
{
  __shared__ __attribute__((aligned(16))) unsigned short sMem[4*34*SSTR]; // 37 KB: conv halo, then A-tile
  __shared__ float sWf[9*LH];
  __shared__ float sInp[64];

  int t = threadIdx.x, blk = blockIdx.x;
  int pair = blk & 15, b = blk >> 4;
  int y0 = pair*2;          // first image row of this block's pair
  int r0 = blk*2;           // global row
  int p0 = r0*MM;           // global pixel base of the 64-px strip
  int wave = t >> 6, l = t & 63, m16 = l & 15, quad = l >> 4;

  // ---- phase P: weight prep into fragment-linear bf16 ------------------
  for (int id = blk*256 + t; id < 360960; id += NBLK*256){
    if (id < 294912){
      int i2 = (id < 147456) ? id : id - 147456;
      int frag = i2 >> 9, rem = i2 & 511, ll = rem >> 3, e = rem & 7;
      int kk = frag >> 5, ct = (frag >> 2) & 7, kc = frag & 3;
      int co = ct*16 + (ll & 15), ci = kc*32 + ((ll >> 4) << 3) + e;
      const float* src = (id < 147456) ? W_h0 : W_c0;
      unsigned short* dst = (id < 147456) ? wc0 : wc1;
      dst[i2] = f2bf(src[(kk<<14) + ci*128 + co]);
    } else if (id < 360448){
      int i2 = id - 294912;
      int frag = i2 >> 9, rem = i2 & 511, ll = rem >> 3, e = rem & 7;
      int q = frag >> 5, ct = (frag >> 2) & 7, kc = frag & 3;
      int rw = q*128 + ct*16 + (ll & 15), col = kc*32 + ((ll >> 4) << 3) + e;
      whhf[i2] = f2bf(Whh[rw*128 + col]);
    } else {
      int j = id - 360448;
      bsum[j] = bih[j] + bhh[j];
    }
  }
  for (int id = t; id < 9*LH; id += 256) sWf[id] = Wf[id];

  // ---- phase H: hid for own 2 rows --------------------------------------
  {
    int ch = t & 127, pxg = t >> 7;
    for (int rr = 0; rr < 2; rr++){
      int y = y0 + rr;
      for (int i = 0; i < 16; i++){
        int x = pxg*16 + i;
        float acc = b_hid[ch];
        #pragma unroll
        for (int ky=0; ky<3; ky++){
          int yy = y + ky - 1; if (yy < 0 || yy >= MM) continue;
          #pragma unroll
          for (int kx=0; kx<3; kx++){
            int xx = x + kx - 1; if (xx < 0 || xx >= MM) continue;
            int gi = (b*MM + yy)*MM + xx;
            int wb = ((ky*3+kx)*2)*LH + ch;
            acc += mp[gi] * W_hid[wb] + gl[gi] * W_hid[wb + LH];
          }
        }
        hidb[(size_t)(p0 + rr*MM + x)*LH + ch] = f2bf(acc);
      }
    }
  }
  __syncthreads();
  if (t == 0) set_flag(&flags[blk*FSTR], 1);
  wait_flag(&flags[t*FSTR], 1);        // full-grid: prep + all hid done
  __syncthreads();

  // ---- phase C: h0 & c0 convs for the row pair --------------------------
  {
    int px = t >> 3, ch0 = (t & 7) * 16;
    for (int k = 0; k < 4; k++){
      int iy = y0 - 1 + k;
      uint4 v0 = make_uint4(0,0,0,0), v1 = v0;
      if (iy >= 0 && iy < MM){
        const unsigned short* src = hidb + ((size_t)((b*MM+iy)*MM + px))*LH + ch0;
        v0 = *(const uint4*)src; v1 = *(const uint4*)(src + 8);
      }
      *(uint4*)&sMem[(k*34 + px + 1)*SSTR + ch0]     = v0;
      *(uint4*)&sMem[(k*34 + px + 1)*SSTR + ch0 + 8] = v1;
      if (t < 32){
        int col = (t >> 4) * 33; int c8 = (t & 15) * 8;
        *(uint4*)&sMem[(k*34 + col)*SSTR + c8] = make_uint4(0,0,0,0);
      }
    }
  }
  __syncthreads();

  float c_reg[2][2][2][4];   // [half][mt][nt][r] — lives across all steps
  for (int h = 0; h < 2; h++){
    floatx4 acch[2][2], accc[2][2];
    #pragma unroll
    for (int mt=0;mt<2;mt++)
      #pragma unroll
      for (int nt=0;nt<2;nt++){ acch[mt][nt] = (floatx4){0.f,0.f,0.f,0.f};
                                accc[mt][nt] = (floatx4){0.f,0.f,0.f,0.f}; }
    #pragma unroll
    for (int kk=0; kk<9; kk++){
      int ky = kk/3, kx = kk%3;
      #pragma unroll
      for (int kc=0; kc<4; kc++){
        bf16x8 a0 = *(const bf16x8*)&sMem[((h+ky)*34 + m16      + kx)*SSTR + kc*32 + quad*8];
        bf16x8 a1 = *(const bf16x8*)&sMem[((h+ky)*34 + m16 + 16 + kx)*SSTR + kc*32 + quad*8];
        #pragma unroll
        for (int nt=0; nt<2; nt++){
          int frag = ((kk*8 + (wave*2 + nt))*4 + kc);
          bf16x8 b0 = *(const bf16x8*)(wc0 + (frag << 9) + l*8);
          bf16x8 b1 = *(const bf16x8*)(wc1 + (frag << 9) + l*8);
          acch[0][nt] = __builtin_amdgcn_mfma_f32_16x16x32_bf16(a0, b0, acch[0][nt], 0,0,0);
          acch[1][nt] = __builtin_amdgcn_mfma_f32_16x16x32_bf16(a1, b0, acch[1][nt], 0,0,0);
          accc[0][nt] = __builtin_amdgcn_mfma_f32_16x16x32_bf16(a0, b1, accc[0][nt], 0,0,0);
          accc[1][nt] = __builtin_amdgcn_mfma_f32_16x16x32_bf16(a1, b1, accc[1][nt], 0,0,0);
        }
      }
    }
    #pragma unroll
    for (int nt=0; nt<2; nt++){
      int co = wave*32 + nt*16 + m16;
      float bh = b_h0[co], bc = b_c0[co];
      #pragma unroll
      for (int mt=0; mt<2; mt++){
        #pragma unroll
        for (int r=0; r<4; r++){
          int x = mt*16 + quad*4 + r;
          c_reg[h][mt][nt][r] = accc[mt][nt][r] + bc;
          hA[(size_t)(p0 + h*MM + x)*LH + co] = f2bf(acch[mt][nt][r] + bh);
        }
      }
    }
  }
  __syncthreads();
  if (t == 0) set_flag(&flags[blk*FSTR], 2);

  // W_hh^T fragments -> registers; epilogue consts -> registers
  bf16x8 bfr[4][2][4];   // [q][nt][kc]
  #pragma unroll
  for (int q=0;q<4;q++)
    #pragma unroll
    for (int nt=0;nt<2;nt++)
      #pragma unroll
      for (int kc=0;kc<4;kc++){
        int frag = ((q*8 + (wave*2 + nt))*4 + kc);
        bfr[q][nt][kc] = *(const bf16x8*)(whhf + (frag << 9) + l*8);
      }
  float wvq[2][4], bsq[2][4];
  #pragma unroll
  for (int nt=0;nt<2;nt++){
    int ch = wave*32 + nt*16 + m16;
    #pragma unroll
    for (int q=0;q<4;q++){ int g = q*128 + ch; wvq[nt][q] = wih[g]; bsq[nt][q] = bsum[g]; }
  }
  float bf0 = bfs[0];

  // ---- 15 LSTM steps -----------------------------------------------------
  const unsigned short* hin = hA; unsigned short* hout = hB;
  bool hasL = (pair > 0), hasR = (pair < 15);
  for (int s = 0; s < NSTEPS; s++){
    if (t == 0 && hasL) wait_flag(&flags[(blk-1)*FSTR], 2+s);
    if (t == 1 && hasR) wait_flag(&flags[(blk+1)*FSTR], 2+s);
    __syncthreads();

    // stage own 64-px strip of h into LDS (A-tile)
    {
      int px2 = t >> 3, ch0 = (t & 7) * 16;
      #pragma unroll
      for (int p=0; p<2; p++){
        int sp = p*32 + px2;
        const unsigned short* src = hin + (size_t)(p0 + sp)*LH + ch0;
        *(uint4*)&sMem[sp*SSTR + ch0]     = *(const uint4*)src;
        *(uint4*)&sMem[sp*SSTR + ch0 + 8] = *(const uint4*)(src + 8);
      }
    }
    // wf scalar-gate conv: 8 lanes/px, 2 passes of 32 px
    {
      int s8 = t & 7;
      #pragma unroll
      for (int p=0; p<2; p++){
        int sp = p*32 + (t >> 3);
        int iy = y0 + (sp >> 5), x = sp & 31;
        float a = 0.f;
        #pragma unroll
        for (int ky=0; ky<3; ky++){
          int gy = iy + ky - 1; if (gy < 0 || gy >= MM) continue;
          #pragma unroll
          for (int kx=0; kx<3; kx++){
            int xx = x + kx - 1; if (xx < 0 || xx >= MM) continue;
            const unsigned short* hp = hin + ((size_t)((b*MM+gy)*MM+xx))*LH + s8*16;
            const float* wp = sWf + (ky*3+kx)*LH + s8*16;
            uint4 h0v = *(const uint4*)hp;
            uint4 h1v = *(const uint4*)(hp + 8);
            const unsigned short* hu = (const unsigned short*)&h0v;
            #pragma unroll
            for (int e=0;e<8;e++) a += bf2f(hu[e]) * wp[e];
            hu = (const unsigned short*)&h1v;
            #pragma unroll
            for (int e=0;e<8;e++) a += bf2f(hu[e]) * wp[8+e];
          }
        }
        a += __shfl_xor(a, 1, 64);
        a += __shfl_xor(a, 2, 64);
        a += __shfl_xor(a, 4, 64);
        if (s8 == 0) sInp[sp] = a + bf0;
      }
    }
    __syncthreads();

    for (int h = 0; h < 2; h++){
      floatx4 acc[2][4][2];
      #pragma unroll
      for (int mt=0;mt<2;mt++)
        #pragma unroll
        for (int q=0;q<4;q++)
          #pragma unroll
          for (int nt=0;nt<2;nt++) acc[mt][q][nt] = (floatx4){0.f,0.f,0.f,0.f};
      #pragma unroll
      for (int kc=0; kc<4; kc++){
        bf16x8 a0 = *(const bf16x8*)&sMem[(h*32 + m16     )*SSTR + kc*32 + quad*8];
        bf16x8 a1 = *(const bf16x8*)&sMem[(h*32 + m16 + 16)*SSTR + kc*32 + quad*8];
        #pragma unroll
        for (int q=0; q<4; q++){
          #pragma unroll
          for (int nt=0; nt<2; nt++){
            acc[0][q][nt] = __builtin_amdgcn_mfma_f32_16x16x32_bf16(a0, bfr[q][nt][kc], acc[0][q][nt], 0,0,0);
            acc[1][q][nt] = __builtin_amdgcn_mfma_f32_16x16x32_bf16(a1, bfr[q][nt][kc], acc[1][q][nt], 0,0,0);
          }
        }
      }
      #pragma unroll
      for (int nt=0; nt<2; nt++){
        int ch = wave*32 + nt*16 + m16;
        #pragma unroll
        for (int mt=0; mt<2; mt++){
          #pragma unroll
          for (int r=0; r<4; r++){
            int pxl = mt*16 + quad*4 + r;
            int sp = h*32 + pxl;
            float iv = sInp[sp];
            float pre0 = acc[mt][0][nt][r] + iv*wvq[nt][0] + bsq[nt][0];
            float pre1 = acc[mt][1][nt][r] + iv*wvq[nt][1] + bsq[nt][1];
            float pre2 = acc[mt][2][nt][r] + iv*wvq[nt][2] + bsq[nt][2];
            float pre3 = acc[mt][3][nt][r] + iv*wvq[nt][3] + bsq[nt][3];
            float ig = sigm(pre0), fg = sigm(pre1), gg = tanh_f(pre2), og = sigm(pre3);
            float cn = fg*c_reg[h][mt][nt][r] + ig*gg;
            c_reg[h][mt][nt][r] = cn;
            hout[(size_t)(p0 + sp)*LH + ch] = f2bf(og * tanh_f(cn));
          }
        }
      }
    }
    __syncthreads();                      // drains all waves' stores (vmcnt) before flag
    if (t == 0) set_flag(&flags[blk*FSTR], 3+s);
    const unsigned short* tmp = hin; hin = hout; hout = (unsigned short*)tmp;
  }

  // ---- policy: logits + 4-way softmax for own 64 px ----------------------
  {
    int s8 = t & 7;
    #pragma unroll
    for (int p=0; p<2; p++){
      int sp = p*32 + (t >> 3);
      const unsigned short* hp = hin + (size_t)(p0 + sp)*LH + s8*16;
      uint4 h0v = *(const uint4*)hp;
      uint4 h1v = *(const uint4*)(hp + 8);
      float la[4] = {0.f,0.f,0.f,0.f};
      const unsigned short* hu = (const unsigned short*)&h0v;
      #pragma unroll
      for (int e=0;e<8;e++){
        int c = s8*16 + e; float hv = bf2f(hu[e]);
        const float* w4 = wpol + c*4;
        la[0]+=hv*w4[0]; la[1]+=hv*w4[1]; la[2]+=hv*w4[2]; la[3]+=hv*w4[3];
      }
      hu = (const unsigned short*)&h1v;
      #pragma unroll
      for (int e=0;e<8;e++){
        int c = s8*16 + 8 + e; float hv = bf2f(hu[e]);
        const float* w4 = wpol + c*4;
        la[0]+=hv*w4[0]; la[1]+=hv*w4[1]; la[2]+=hv*w4[2]; la[3]+=hv*w4[3];
      }
      #pragma unroll
      for (int a=0;a<4;a++){
        la[a] += __shfl_xor(la[a], 1, 64);
        la[a] += __shfl_xor(la[a], 2, 64);
        la[a] += __shfl_xor(la[a], 4, 64);
      }
      if (s8 == 0){
        int y = (r0 + (sp >> 5)) & 31, x = sp & 31;
        float m = fmaxf(fmaxf(la[0],la[1]),fmaxf(la[2],la[3]));
        float e[4]; float sum = 0.f;
        #pragma unroll
        for (int a=0;a<4;a++){ e[a]=__expf(la[a]-m); sum+=e[a]; }
        float inv = 1.f/sum;
        #pragma unroll
        for (int a=0;a<4;a++){
          int o = ((b*4 + a)*MM + y)*MM + x;
          out[o] = la[a];
          out[65536 + o] = e[a]*inv;
        }
      }
    }
  }
}

extern "C" void kernel_launch(void* const* d_in, const int* in_sizes, int n_in,
                              void* d_out, int out_size, void* d_ws, size_t ws_size,
                              hipStream_t stream){
  const float* mp    = (const float*)d_in[0];
  const float* gl    = (const float*)d_in[1];
  const float* W_hid = (const float*)d_in[2];
  const float* b_hid = (const float*)d_in[3];
  const float* W_h0  = (const float*)d_in[4];
  const float* b_h0  = (const float*)d_in[5];
  const float* W_c0  = (const float*)d_in[6];
  const float* b_c0  = (const float*)d_in[7];
  const float* W_f   = (const float*)d_in[8];
  const float* b_f   = (const float*)d_in[9];
  const float* W_ih  = (const float*)d_in[10];
  const float* b_ih  = (const float*)d_in[11];
  const float* W_hh  = (const float*)d_in[12];
  const float* b_hh  = (const float*)d_in[13];
  const float* W_pol = (const float*)d_in[14];
  float* out = (float*)d_out;

  char* ws = (char*)d_ws;
  unsigned short* hA    = (unsigned short*)ws;                          // 4 MB
  unsigned short* hB    = (unsigned short*)(ws + ((size_t) 4<<20));     // 4 MB
  unsigned short* hidb  = (unsigned short*)(ws + ((size_t) 8<<20));     // 4 MB
  unsigned short* whhf  = (unsigned short*)(ws + ((size_t)12<<20));     // 128 KB
  float*          bsum  = (float*)(ws + ((size_t)12<<20) + (128<<10));  // 4 KB
  unsigned short* wc0   = (unsigned short*)(ws + ((size_t)12<<20) + (132<<10)); // 288 KB
  unsigned short* wc1   = (unsigned short*)(ws + ((size_t)12<<20) + (420<<10)); // 288 KB
  int*            flags = (int*)(ws + ((size_t)12<<20) + (708<<10));    // 32 KB

  k_mega<<<NBLK, 256, 0, stream>>>(
      mp, gl, W_hid, b_hid, W_h0, b_h0, W_c0, b_c0, W_f, b_f,
      W_ih, b_ih, W_hh, b_hh, W_pol,
      hA, hB, hidb, wc0, wc1, whhf, bsum, flags, out);
}

// Round 7
// 359.028 us; speedup vs baseline: 1.9797x; 1.9797x over previous
//
#include <hip/hip_runtime.h>

#define BB 16
#define MM 32
#define LH 128
#define NSTEPS 15          // K-1
#define SSTR 136
#define NBLK 256           // 2 rows per block
#define FSTR 32            // flag stride in ints (128 B apart)
#define SIDX(row,pxi,ch) (((row)*34 + (pxi))*SSTR + (ch))

typedef __bf16  bf16x8  __attribute__((ext_vector_type(8)));
typedef float   floatx4 __attribute__((ext_vector_type(4)));
typedef unsigned long long ull;

__device__ __forceinline__ float sigm(float x){ return 1.f/(1.f+__expf(-x)); }
__device__ __forceinline__ float tanh_f(float x){ return 1.f - 2.f/(__expf(2.f*x)+1.f); }

__device__ __forceinline__ unsigned short f2bf(float x){
  union { float f; unsigned u; } v; v.f = x;
  unsigned r = v.u + 0x7FFFu + ((v.u >> 16) & 1u);   // RNE
  return (unsigned short)(r >> 16);
}
__device__ __forceinline__ float bf2f(unsigned short u){
  union { unsigned u2; float f; } v; v.u2 = ((unsigned)u) << 16;
  return v.f;
}

// relaxed device-scope ops: bypass L1/L2, complete at coherent LLC. No fences.
__device__ __forceinline__ void st_dev(ull* p, ull v){
  __hip_atomic_store(p, v, __ATOMIC_RELAXED, __HIP_MEMORY_SCOPE_AGENT);
}
__device__ __forceinline__ ull ld_dev(ull* p){
  return __hip_atomic_load(p, __ATOMIC_RELAXED, __HIP_MEMORY_SCOPE_AGENT);
}
// poison-safe relaxed spin (0xAAAAAAAA == far behind under signed diff)
__device__ __forceinline__ void wait_flag(int* f, int target){
  while ((int)(__hip_atomic_load(f, __ATOMIC_RELAXED, __HIP_MEMORY_SCOPE_AGENT) - target) < 0){
    __builtin_amdgcn_s_sleep(1);
  }
}
__device__ __forceinline__ void set_flag(int* f, int v){
  // callers __syncthreads() first => vmcnt(0) drained => prior st_dev visible at LLC
  __hip_atomic_store(f, v, __ATOMIC_RELAXED, __HIP_MEMORY_SCOPE_AGENT);
}

__global__ __launch_bounds__(256, 1) void k_mega(
    const float* __restrict__ mp,   const float* __restrict__ gl,
    const float* __restrict__ W_hid,const float* __restrict__ b_hid,
    const float* __restrict__ W_h0, const float* __restrict__ b_h0,
    const float* __restrict__ W_c0, const float* __restrict__ b_c0,
    const float* __restrict__ Wf,   const float* __restrict__ bfs,
    const float* __restrict__ wih,  const float* __restrict__ bih,
    const float* __restrict__ Whh,  const float* __restrict__ bhh,
    const float* __restrict__ wpol,
    unsigned short* __restrict__ hA, unsigned short* __restrict__ hB,
    unsigned short* __restrict__ hidb,
    unsigned short* __restrict__ wc0, unsigned short* __restrict__ wc1,
    unsigned short* __restrict__ whhf, float* __restrict__ bsum,
    int* __restrict__ flags, float* __restrict__ out)
{
  __shared__ __attribute__((aligned(16))) unsigned short sH[4*34*SSTR]; // 37 KB
  __shared__ float sWf[9*LH];
  __shared__ float sInp[64];

  int t = threadIdx.x, blk = blockIdx.x;
  int pair = blk & 15, b = blk >> 4;
  int y0 = pair*2;
  int r0 = blk*2;
  int p0 = r0*MM;
  int wave = t >> 6, l = t & 63, m16 = l & 15, quad = l >> 4;
  bool hasL = (pair > 0), hasR = (pair < 15);

  // ---- phase P: weight prep, write-through b64 chunks -------------------
  for (int c = blk*256 + t; c < 90368; c += NBLK*256){
    if (c < 73728){            // two conv weights, 36864 chunks each
      int which = (c >= 36864) ? 1 : 0;
      int cc = which ? c - 36864 : c;
      int i2 = cc*4, frag = i2 >> 9, rem = i2 & 511, ll = rem >> 3, e0 = rem & 7;
      int kk = frag >> 5, ct = (frag >> 2) & 7, kc = frag & 3;
      int co = ct*16 + (ll & 15), ci0 = kc*32 + ((ll >> 4) << 3) + e0;
      const float* src = which ? W_c0 : W_h0;
      ull v = 0;
      #pragma unroll
      for (int j=0;j<4;j++) v |= (ull)f2bf(src[(kk<<14) + (ci0+j)*128 + co]) << (16*j);
      st_dev((ull*)(which ? wc1 : wc0) + cc, v);
    } else if (c < 90112){     // whh, 16384 chunks
      int cc = c - 73728;
      int i2 = cc*4, frag = i2 >> 9, rem = i2 & 511, ll = rem >> 3, e0 = rem & 7;
      int q = frag >> 5, ct = (frag >> 2) & 7, kc = frag & 3;
      int rw = q*128 + ct*16 + (ll & 15), col = kc*32 + ((ll >> 4) << 3) + e0;
      const float* s4 = Whh + rw*128 + col;
      ull v = 0;
      #pragma unroll
      for (int j=0;j<4;j++) v |= (ull)f2bf(s4[j]) << (16*j);
      st_dev((ull*)whhf + cc, v);
    } else {                   // bsum, 256 chunks of 2 fp32
      int cc = c - 90112; int j = cc*2;
      union { float f[2]; ull u; } pv;
      pv.f[0] = bih[j] + bhh[j]; pv.f[1] = bih[j+1] + bhh[j+1];
      st_dev((ull*)bsum + cc, pv.u);
    }
  }
  for (int id = t; id < 9*LH; id += 256) sWf[id] = Wf[id];

  // ---- phase H: hid for own 2 rows -> LDS temp -> write-through global --
  {
    int ch = t & 127, pxg = t >> 7;
    for (int rr = 0; rr < 2; rr++){
      int y = y0 + rr;
      for (int i = 0; i < 16; i++){
        int x = pxg*16 + i;
        float acc = b_hid[ch];
        #pragma unroll
        for (int ky=0; ky<3; ky++){
          int yy = y + ky - 1; if (yy < 0 || yy >= MM) continue;
          #pragma unroll
          for (int kx=0; kx<3; kx++){
            int xx = x + kx - 1; if (xx < 0 || xx >= MM) continue;
            int gi = (b*MM + yy)*MM + xx;
            int wb = ((ky*3+kx)*2)*LH + ch;
            acc += mp[gi] * W_hid[wb] + gl[gi] * W_hid[wb + LH];
          }
        }
        sH[(rr*32 + x)*128 + ch] = f2bf(acc);   // linear temp layout
      }
    }
  }
  __syncthreads();
  #pragma unroll
  for (int j=0;j<8;j++){
    int chunk = j*256 + t;                      // 2048 chunks = 2 rows
    st_dev((ull*)hidb + p0*32 + chunk, *(ull*)&sH[chunk*4]);
  }
  __syncthreads();                              // drains vmcnt: prep+hid visible
  if (t == 0) set_flag(&flags[blk*FSTR], 1);
  wait_flag(&flags[t*FSTR], 1);                 // full grid
  __syncthreads();

  // ---- phase C: stage 4 hid rows (padded halo) via LLC loads ------------
  #pragma unroll
  for (int j=0;j<16;j++){
    int chunk = j*256 + t;                      // 4096 chunks = 4 rows
    int k = chunk >> 10, w = chunk & 1023, px = w >> 5, c4 = w & 31;
    int iy = y0 - 1 + k;
    ull v = 0;
    if (iy >= 0 && iy < MM) v = ld_dev((ull*)hidb + (((b*MM + iy)*MM) + px)*32 + c4);
    *(ull*)&sH[SIDX(k, px+1, c4*4)] = v;
  }
  { int k = t >> 6, col = ((t >> 5) & 1) ? 33 : 0, c4 = t & 31;  // t<256 exactly
    *(ull*)&sH[SIDX(k, col, c4*4)] = 0; }
  __syncthreads();

  // ---- h0 & c0 convs; both halves before any LDS overwrite --------------
  float c_reg[2][2][2][4];
  floatx4 acch[2][2][2], accc[2][2][2];
  #pragma unroll
  for (int h=0;h<2;h++)
    #pragma unroll
    for (int mt=0;mt<2;mt++)
      #pragma unroll
      for (int nt=0;nt<2;nt++){ acch[h][mt][nt] = (floatx4){0.f,0.f,0.f,0.f};
                                accc[h][mt][nt] = (floatx4){0.f,0.f,0.f,0.f}; }
  for (int h = 0; h < 2; h++){
    #pragma unroll
    for (int kk=0; kk<9; kk++){
      int ky = kk/3, kx = kk%3;
      #pragma unroll
      for (int kc=0; kc<4; kc++){
        bf16x8 a0 = *(const bf16x8*)&sH[SIDX(h+ky, m16      + kx, kc*32 + quad*8)];
        bf16x8 a1 = *(const bf16x8*)&sH[SIDX(h+ky, m16 + 16 + kx, kc*32 + quad*8)];
        #pragma unroll
        for (int nt=0; nt<2; nt++){
          int frag = ((kk*8 + (wave*2 + nt))*4 + kc);
          bf16x8 b0 = *(const bf16x8*)(wc0 + (frag << 9) + l*8);
          bf16x8 b1 = *(const bf16x8*)(wc1 + (frag << 9) + l*8);
          acch[h][0][nt] = __builtin_amdgcn_mfma_f32_16x16x32_bf16(a0, b0, acch[h][0][nt], 0,0,0);
          acch[h][1][nt] = __builtin_amdgcn_mfma_f32_16x16x32_bf16(a1, b0, acch[h][1][nt], 0,0,0);
          accc[h][0][nt] = __builtin_amdgcn_mfma_f32_16x16x32_bf16(a0, b1, accc[h][0][nt], 0,0,0);
          accc[h][1][nt] = __builtin_amdgcn_mfma_f32_16x16x32_bf16(a1, b1, accc[h][1][nt], 0,0,0);
        }
      }
    }
  }
  __syncthreads();                              // all conv reads done
  #pragma unroll
  for (int h=0;h<2;h++)
    #pragma unroll
    for (int nt=0; nt<2; nt++){
      int co = wave*32 + nt*16 + m16;
      float bh = b_h0[co], bc = b_c0[co];
      #pragma unroll
      for (int mt=0; mt<2; mt++)
        #pragma unroll
        for (int r=0; r<4; r++){
          int x = mt*16 + quad*4 + r;
          c_reg[h][mt][nt][r] = accc[h][mt][nt][r] + bc;
          sH[SIDX(1+h, x+1, co)] = f2bf(acch[h][mt][nt][r] + bh);
        }
    }
  __syncthreads();
  #pragma unroll
  for (int j=0;j<8;j++){                        // publish h0 rows
    int chunk = j*256 + t;
    int r = chunk >> 10, w = chunk & 1023, px = w >> 5, c4 = w & 31;
    st_dev((ull*)hA + (p0 + r*32 + px)*32 + c4, *(ull*)&sH[SIDX(1+r, px+1, c4*4)]);
  }
  if (!hasL){
    #pragma unroll
    for (int j=0;j<4;j++){
      int chunk = j*256 + t;
      *(ull*)&sH[SIDX(0, (chunk>>5)+1, (chunk&31)*4)] = 0;
    }
  }
  if (!hasR){
    #pragma unroll
    for (int j=0;j<4;j++){
      int chunk = j*256 + t;
      *(ull*)&sH[SIDX(3, (chunk>>5)+1, (chunk&31)*4)] = 0;
    }
  }
  __syncthreads();                              // vmcnt drained
  if (t == 0) set_flag(&flags[blk*FSTR], 2);

  // W_hh^T fragments + epilogue consts -> registers
  bf16x8 bfr[4][2][4];
  #pragma unroll
  for (int q=0;q<4;q++)
    #pragma unroll
    for (int nt=0;nt<2;nt++)
      #pragma unroll
      for (int kc=0;kc<4;kc++){
        int frag = ((q*8 + (wave*2 + nt))*4 + kc);
        bfr[q][nt][kc] = *(const bf16x8*)(whhf + (frag << 9) + l*8);
      }
  float wvq[2][4], bsq[2][4];
  #pragma unroll
  for (int nt=0;nt<2;nt++){
    int ch = wave*32 + nt*16 + m16;
    #pragma unroll
    for (int q=0;q<4;q++){ int g = q*128 + ch; wvq[nt][q] = wih[g]; bsq[nt][q] = bsum[g]; }
  }
  float bf0 = bfs[0];
  unsigned short* hb[2] = {hA, hB};

  // ---- 15 LSTM steps (h lives in LDS; only halos go through LLC) --------
  for (int s = 0; s < NSTEPS; s++){
    if (t == 0 && hasL) wait_flag(&flags[(blk-1)*FSTR], 2+s);
    if (t == 1 && hasR) wait_flag(&flags[(blk+1)*FSTR], 2+s);
    __syncthreads();
    // load halo rows 0,3 from neighbors
    #pragma unroll
    for (int j=0;j<8;j++){
      int chunk = j*256 + t;                    // 2048 = 2 rows
      int rsel = chunk >> 10, w = chunk & 1023, px = w >> 5, c4 = w & 31;
      bool ok = rsel ? hasR : hasL;
      if (ok){
        int grow = r0 + (rsel ? 2 : -1);
        ull v = ld_dev((ull*)hb[s&1] + (grow*32 + px)*32 + c4);
        *(ull*)&sH[SIDX(rsel ? 3 : 0, px+1, c4*4)] = v;
      }
    }
    __syncthreads();

    // wf conv from LDS (branch-free taps thanks to pads/zero rows)
    {
      int px = t >> 3, s8 = t & 7;
      #pragma unroll
      for (int p=0; p<2; p++){
        float a = 0.f;
        #pragma unroll
        for (int ky=0; ky<3; ky++){
          #pragma unroll
          for (int kx=0; kx<3; kx++){
            int base = SIDX(p + ky, px + kx, s8*16);
            uint4 h0v = *(const uint4*)&sH[base];
            uint4 h1v = *(const uint4*)&sH[base + 8];
            const float* wp = sWf + (ky*3+kx)*LH + s8*16;
            const unsigned short* hu = (const unsigned short*)&h0v;
            #pragma unroll
            for (int e=0;e<8;e++) a += bf2f(hu[e]) * wp[e];
            hu = (const unsigned short*)&h1v;
            #pragma unroll
            for (int e=0;e<8;e++) a += bf2f(hu[e]) * wp[8+e];
          }
        }
        a += __shfl_xor(a, 1, 64);
        a += __shfl_xor(a, 2, 64);
        a += __shfl_xor(a, 4, 64);
        if (s8 == 0) sInp[p*32 + px] = a + bf0;
      }
    }
    // A-frags for half 0 (row 1) must be read before its overwrite
    bf16x8 af0[4], af1[4];
    #pragma unroll
    for (int kc=0;kc<4;kc++){
      af0[kc] = *(const bf16x8*)&sH[SIDX(1, m16+1,  kc*32 + quad*8)];
      af1[kc] = *(const bf16x8*)&sH[SIDX(1, m16+17, kc*32 + quad*8)];
    }
    __syncthreads();   // B1: all reads of row1 (wf + af) done

    for (int h = 0; h < 2; h++){
      floatx4 acc[2][4][2];
      #pragma unroll
      for (int mt=0;mt<2;mt++)
        #pragma unroll
        for (int q=0;q<4;q++)
          #pragma unroll
          for (int nt=0;nt<2;nt++) acc[mt][q][nt] = (floatx4){0.f,0.f,0.f,0.f};
      #pragma unroll
      for (int kc=0; kc<4; kc++){
        #pragma unroll
        for (int q=0; q<4; q++){
          #pragma unroll
          for (int nt=0; nt<2; nt++){
            acc[0][q][nt] = __builtin_amdgcn_mfma_f32_16x16x32_bf16(af0[kc], bfr[q][nt][kc], acc[0][q][nt], 0,0,0);
            acc[1][q][nt] = __builtin_amdgcn_mfma_f32_16x16x32_bf16(af1[kc], bfr[q][nt][kc], acc[1][q][nt], 0,0,0);
          }
        }
      }
      #pragma unroll
      for (int nt=0; nt<2; nt++){
        int ch = wave*32 + nt*16 + m16;
        #pragma unroll
        for (int mt=0; mt<2; mt++){
          #pragma unroll
          for (int r=0; r<4; r++){
            int pxl = mt*16 + quad*4 + r;
            float iv = sInp[h*32 + pxl];
            float pre0 = acc[mt][0][nt][r] + iv*wvq[nt][0] + bsq[nt][0];
            float pre1 = acc[mt][1][nt][r] + iv*wvq[nt][1] + bsq[nt][1];
            float pre2 = acc[mt][2][nt][r] + iv*wvq[nt][2] + bsq[nt][2];
            float pre3 = acc[mt][3][nt][r] + iv*wvq[nt][3] + bsq[nt][3];
            float ig = sigm(pre0), fg = sigm(pre1), gg = tanh_f(pre2), og = sigm(pre3);
            float cn = fg*c_reg[h][mt][nt][r] + ig*gg;
            c_reg[h][mt][nt][r] = cn;
            sH[SIDX(1+h, pxl+1, ch)] = f2bf(og * tanh_f(cn));
          }
        }
      }
      if (h == 0){
        // A-frags for half 1 (row 2, still old h_s) before B2
        #pragma unroll
        for (int kc=0;kc<4;kc++){
          af0[kc] = *(const bf16x8*)&sH[SIDX(2, m16+1,  kc*32 + quad*8)];
          af1[kc] = *(const bf16x8*)&sH[SIDX(2, m16+17, kc*32 + quad*8)];
        }
        __syncthreads();  // B2: all reads of row2 done before its overwrite
      }
    }
    __syncthreads();     // B3: rows 1,2 hold h_{s+1}

    if (s < NSTEPS-1){
      #pragma unroll
      for (int j=0;j<8;j++){
        int chunk = j*256 + t;
        int r = chunk >> 10, w = chunk & 1023, px = w >> 5, c4 = w & 31;
        st_dev((ull*)hb[(s+1)&1] + (p0 + r*32 + px)*32 + c4,
               *(ull*)&sH[SIDX(1+r, px+1, c4*4)]);
      }
      __syncthreads();   // vmcnt drained
      if (t == 0) set_flag(&flags[blk*FSTR], 3+s);
    }
  }

  // ---- policy from LDS rows 1,2 -----------------------------------------
  {
    int px = t >> 3, s8 = t & 7;
    #pragma unroll
    for (int p=0; p<2; p++){
      int base = SIDX(1+p, px+1, s8*16);
      uint4 h0v = *(const uint4*)&sH[base];
      uint4 h1v = *(const uint4*)&sH[base + 8];
      float la[4] = {0.f,0.f,0.f,0.f};
      const unsigned short* hu = (const unsigned short*)&h0v;
      #pragma unroll
      for (int e=0;e<8;e++){
        int c = s8*16 + e; float hv = bf2f(hu[e]);
        const float* w4 = wpol + c*4;
        la[0]+=hv*w4[0]; la[1]+=hv*w4[1]; la[2]+=hv*w4[2]; la[3]+=hv*w4[3];
      }
      hu = (const unsigned short*)&h1v;
      #pragma unroll
      for (int e=0;e<8;e++){
        int c = s8*16 + 8 + e; float hv = bf2f(hu[e]);
        const float* w4 = wpol + c*4;
        la[0]+=hv*w4[0]; la[1]+=hv*w4[1]; la[2]+=hv*w4[2]; la[3]+=hv*w4[3];
      }
      #pragma unroll
      for (int a=0;a<4;a++){
        la[a] += __shfl_xor(la[a], 1, 64);
        la[a] += __shfl_xor(la[a], 2, 64);
        la[a] += __shfl_xor(la[a], 4, 64);
      }
      if (s8 == 0){
        int y = y0 + p, x = px;
        float m = fmaxf(fmaxf(la[0],la[1]),fmaxf(la[2],la[3]));
        float e[4]; float sum = 0.f;
        #pragma unroll
        for (int a=0;a<4;a++){ e[a]=__expf(la[a]-m); sum+=e[a]; }
        float inv = 1.f/sum;
        #pragma unroll
        for (int a=0;a<4;a++){
          int o = ((b*4 + a)*MM + y)*MM + x;
          out[o] = la[a];
          out[65536 + o] = e[a]*inv;
        }
      }
    }
  }
}

extern "C" void kernel_launch(void* const* d_in, const int* in_sizes, int n_in,
                              void* d_out, int out_size, void* d_ws, size_t ws_size,
                              hipStream_t stream){
  const float* mp    = (const float*)d_in[0];
  const float* gl    = (const float*)d_in[1];
  const float* W_hid = (const float*)d_in[2];
  const float* b_hid = (const float*)d_in[3];
  const float* W_h0  = (const float*)d_in[4];
  const float* b_h0  = (const float*)d_in[5];
  const float* W_c0  = (const float*)d_in[6];
  const float* b_c0  = (const float*)d_in[7];
  const float* W_f   = (const float*)d_in[8];
  const float* b_f   = (const float*)d_in[9];
  const float* W_ih  = (const float*)d_in[10];
  const float* b_ih  = (const float*)d_in[11];
  const float* W_hh  = (const float*)d_in[12];
  const float* b_hh  = (const float*)d_in[13];
  const float* W_pol = (const float*)d_in[14];
  float* out = (float*)d_out;

  char* ws = (char*)d_ws;
  unsigned short* hA    = (unsigned short*)ws;                          // 4 MB
  unsigned short* hB    = (unsigned short*)(ws + ((size_t) 4<<20));     // 4 MB
  unsigned short* hidb  = (unsigned short*)(ws + ((size_t) 8<<20));     // 4 MB
  unsigned short* whhf  = (unsigned short*)(ws + ((size_t)12<<20));     // 128 KB
  float*          bsum  = (float*)(ws + ((size_t)12<<20) + (128<<10));  // 4 KB
  unsigned short* wc0   = (unsigned short*)(ws + ((size_t)12<<20) + (132<<10)); // 288 KB
  unsigned short* wc1   = (unsigned short*)(ws + ((size_t)12<<20) + (420<<10)); // 288 KB
  int*            flags = (int*)(ws + ((size_t)12<<20) + (708<<10));    // 32 KB

  k_mega<<<NBLK, 256, 0, stream>>>(
      mp, gl, W_hid, b_hid, W_h0, b_h0, W_c0, b_c0, W_f, b_f,
      W_ih, b_ih, W_hh, b_hh, W_pol,
      hA, hB, hidb, wc0, wc1, whhf, bsum, flags, out);
}

// Round 8
// 261.728 us; speedup vs baseline: 2.7157x; 1.3718x over previous
//
#include <hip/hip_runtime.h>

#define BB 16
#define MM 32
#define LH 128
#define NSTEPS 15          // K-1
#define SSTR 136
#define NBLK 256           // 2 rows per block, 512 threads (8 waves)
#define FSTR 32            // flag stride in ints (128 B apart)
#define SIDX(row,pxi,ch) (((row)*34 + (pxi))*SSTR + (ch))

typedef __bf16  bf16x8  __attribute__((ext_vector_type(8)));
typedef float   floatx4 __attribute__((ext_vector_type(4)));
typedef unsigned long long ull;

__device__ __forceinline__ float sigm(float x){ return 1.f/(1.f+__expf(-x)); }
__device__ __forceinline__ float tanh_f(float x){ return 1.f - 2.f/(__expf(2.f*x)+1.f); }

__device__ __forceinline__ unsigned short f2bf(float x){
  union { float f; unsigned u; } v; v.f = x;
  unsigned r = v.u + 0x7FFFu + ((v.u >> 16) & 1u);   // RNE
  return (unsigned short)(r >> 16);
}
__device__ __forceinline__ float bf2f(unsigned short u){
  union { unsigned u2; float f; } v; v.u2 = ((unsigned)u) << 16;
  return v.f;
}

// relaxed device-scope ops: complete at coherent point, no L2 wb/inv storms
__device__ __forceinline__ void st_dev(ull* p, ull v){
  __hip_atomic_store(p, v, __ATOMIC_RELAXED, __HIP_MEMORY_SCOPE_AGENT);
}
__device__ __forceinline__ ull ld_dev(ull* p){
  return __hip_atomic_load(p, __ATOMIC_RELAXED, __HIP_MEMORY_SCOPE_AGENT);
}
// poison-safe relaxed spin (0xAAAAAAAA == far behind under signed diff)
__device__ __forceinline__ void wait_flag(int* f, int target){
  while ((int)(__hip_atomic_load(f, __ATOMIC_RELAXED, __HIP_MEMORY_SCOPE_AGENT) - target) < 0){
    __builtin_amdgcn_s_sleep(1);
  }
}
__device__ __forceinline__ void set_flag(int* f, int v){
  // callers __syncthreads() first => vmcnt(0) drained => prior st_dev visible
  __hip_atomic_store(f, v, __ATOMIC_RELAXED, __HIP_MEMORY_SCOPE_AGENT);
}

__global__ __launch_bounds__(512, 2) void k_mega(
    const float* __restrict__ mp,   const float* __restrict__ gl,
    const float* __restrict__ W_hid,const float* __restrict__ b_hid,
    const float* __restrict__ W_h0, const float* __restrict__ b_h0,
    const float* __restrict__ W_c0, const float* __restrict__ b_c0,
    const float* __restrict__ Wf,   const float* __restrict__ bfs,
    const float* __restrict__ wih,  const float* __restrict__ bih,
    const float* __restrict__ Whh,  const float* __restrict__ bhh,
    const float* __restrict__ wpol,
    unsigned short* __restrict__ hA, unsigned short* __restrict__ hB,
    unsigned short* __restrict__ hidb,
    unsigned short* __restrict__ wc0, unsigned short* __restrict__ wc1,
    unsigned short* __restrict__ whhf, float* __restrict__ bsum,
    int* __restrict__ flags, float* __restrict__ out)
{
  __shared__ __attribute__((aligned(16))) unsigned short sH[4*34*SSTR]; // 37 KB
  __shared__ float sWf[9*LH];
  __shared__ float sInp[64];

  int t = threadIdx.x, blk = blockIdx.x;
  int pair = blk & 15, b = blk >> 4;
  int y0 = pair*2;          // first image row of the pair
  int r0 = blk*2;           // global row
  int p0 = r0*MM;           // global pixel base (64-px strip)
  int wave = t >> 6, l = t & 63, m16 = l & 15, quad = l >> 4;
  bool hasL = (pair > 0), hasR = (pair < 15);
  int ch = wave*16 + m16;   // this wave's 16-ch tile (per gate / per conv out)

  // ---- phase P: weight prep into fragment-linear bf16 -------------------
  for (int c = blk*512 + t; c < 90368; c += NBLK*512){
    if (c < 73728){
      int which = (c >= 36864) ? 1 : 0;
      int cc = which ? c - 36864 : c;
      int i2 = cc*4, frag = i2 >> 9, rem = i2 & 511, ll = rem >> 3, e0 = rem & 7;
      int kk = frag >> 5, ct = (frag >> 2) & 7, kc = frag & 3;
      int co = ct*16 + (ll & 15), ci0 = kc*32 + ((ll >> 4) << 3) + e0;
      const float* src = which ? W_c0 : W_h0;
      ull v = 0;
      #pragma unroll
      for (int j=0;j<4;j++) v |= (ull)f2bf(src[(kk<<14) + (ci0+j)*128 + co]) << (16*j);
      st_dev((ull*)(which ? wc1 : wc0) + cc, v);
    } else if (c < 90112){
      int cc = c - 73728;
      int i2 = cc*4, frag = i2 >> 9, rem = i2 & 511, ll = rem >> 3, e0 = rem & 7;
      int q = frag >> 5, ct = (frag >> 2) & 7, kc = frag & 3;
      int rw = q*128 + ct*16 + (ll & 15), col = kc*32 + ((ll >> 4) << 3) + e0;
      const float* s4 = Whh + rw*128 + col;
      ull v = 0;
      #pragma unroll
      for (int j=0;j<4;j++) v |= (ull)f2bf(s4[j]) << (16*j);
      st_dev((ull*)whhf + cc, v);
    } else {
      int cc = c - 90112; int j = cc*2;
      union { float f[2]; ull u; } pv;
      pv.f[0] = bih[j] + bhh[j]; pv.f[1] = bih[j+1] + bhh[j+1];
      st_dev((ull*)bsum + cc, pv.u);
    }
  }
  for (int id = t; id < 9*LH; id += 512) sWf[id] = Wf[id];

  // ---- phase H: hid for own 2 rows -> LDS temp -> write-through ---------
  {
    int hch = t & 127, g = t >> 7;        // g in 0..3
    int rr = g >> 1, xh = (g & 1)*16;
    int y = y0 + rr;
    for (int i = 0; i < 16; i++){
      int x = xh + i;
      float acc = b_hid[hch];
      #pragma unroll
      for (int ky=0; ky<3; ky++){
        int yy = y + ky - 1; if (yy < 0 || yy >= MM) continue;
        #pragma unroll
        for (int kx=0; kx<3; kx++){
          int xx = x + kx - 1; if (xx < 0 || xx >= MM) continue;
          int gi = (b*MM + yy)*MM + xx;
          int wb = ((ky*3+kx)*2)*LH + hch;
          acc += mp[gi] * W_hid[wb] + gl[gi] * W_hid[wb + LH];
        }
      }
      sH[(rr*32 + x)*128 + hch] = f2bf(acc);
    }
  }
  __syncthreads();
  #pragma unroll
  for (int j=0;j<4;j++){
    int chunk = j*512 + t;                // 2048 chunks = 2 rows
    st_dev((ull*)hidb + p0*32 + chunk, *(ull*)&sH[chunk*4]);
  }
  __syncthreads();
  if (t == 0) set_flag(&flags[blk*FSTR], 1);
  if (t < NBLK) wait_flag(&flags[t*FSTR], 1);   // full grid
  __syncthreads();

  // ---- phase C: stage 4 hid rows (halo-padded) --------------------------
  #pragma unroll
  for (int j=0;j<8;j++){
    int chunk = j*512 + t;                // 4096 chunks = 4 rows
    int k = chunk >> 10, w = chunk & 1023, px = w >> 5, c4 = w & 31;
    int iy = y0 - 1 + k;
    ull v = 0;
    if (iy >= 0 && iy < MM) v = ld_dev((ull*)hidb + (((b*MM + iy)*MM) + px)*32 + c4);
    *(ull*)&sH[SIDX(k, px+1, c4*4)] = v;
  }
  if (t < 256){
    int k = t >> 6, col = ((t >> 5) & 1) ? 33 : 0, c4 = t & 31;
    *(ull*)&sH[SIDX(k, col, c4*4)] = 0;
  }
  __syncthreads();

  // ---- h0 & c0 convs: M=64 px, this wave's 16 out-ch --------------------
  float c_reg[4][4];        // [mt][r] — persists across all steps
  {
    floatx4 acch[4], accc[4];
    #pragma unroll
    for (int mt=0;mt<4;mt++){ acch[mt] = (floatx4){0.f,0.f,0.f,0.f};
                              accc[mt] = (floatx4){0.f,0.f,0.f,0.f}; }
    #pragma unroll
    for (int kk=0; kk<9; kk++){
      int ky = kk/3, kx = kk%3;
      #pragma unroll
      for (int kc=0; kc<4; kc++){
        int frag = ((kk*8 + wave)*4 + kc);
        bf16x8 b0 = *(const bf16x8*)(wc0 + (frag << 9) + l*8);
        bf16x8 b1 = *(const bf16x8*)(wc1 + (frag << 9) + l*8);
        #pragma unroll
        for (int mt=0; mt<4; mt++){
          bf16x8 a = *(const bf16x8*)&sH[SIDX((mt>>1)+ky, m16 + (mt&1)*16 + kx, kc*32 + quad*8)];
          acch[mt] = __builtin_amdgcn_mfma_f32_16x16x32_bf16(a, b0, acch[mt], 0,0,0);
          accc[mt] = __builtin_amdgcn_mfma_f32_16x16x32_bf16(a, b1, accc[mt], 0,0,0);
        }
      }
    }
    __syncthreads();                      // all conv reads done
    float bh = b_h0[ch], bc = b_c0[ch];
    #pragma unroll
    for (int mt=0; mt<4; mt++)
      #pragma unroll
      for (int r=0; r<4; r++){
        int px = mt*16 + quad*4 + r;      // 0..63
        c_reg[mt][r] = accc[mt][r] + bc;
        sH[SIDX(1+(px>>5), (px&31)+1, ch)] = f2bf(acch[mt][r] + bh);
      }
  }
  __syncthreads();
  #pragma unroll
  for (int j=0;j<4;j++){                  // publish h0 rows
    int chunk = j*512 + t;
    int r = chunk >> 10, w = chunk & 1023, px = w >> 5, c4 = w & 31;
    st_dev((ull*)hA + (p0 + r*32 + px)*32 + c4, *(ull*)&sH[SIDX(1+r, px+1, c4*4)]);
  }
  // boundary zero halo rows 0/3 (stay zero forever at image edges)
  if (!hasL){
    #pragma unroll
    for (int j=0;j<2;j++){
      int chunk = j*512 + t;
      *(ull*)&sH[SIDX(0, (chunk>>5)+1, (chunk&31)*4)] = 0;
    }
  }
  if (!hasR){
    #pragma unroll
    for (int j=0;j<2;j++){
      int chunk = j*512 + t;
      *(ull*)&sH[SIDX(3, (chunk>>5)+1, (chunk&31)*4)] = 0;
    }
  }
  __syncthreads();                        // vmcnt drained
  if (t == 0) set_flag(&flags[blk*FSTR], 2);

  // W_hh^T fragments (this wave: 16 ch x 4 gates x 4 kc) + epilogue consts
  bf16x8 bfr[4][4];   // [q][kc] — 64 VGPRs, constant across steps
  #pragma unroll
  for (int q=0;q<4;q++)
    #pragma unroll
    for (int kc=0;kc<4;kc++){
      int frag = ((q*8 + wave)*4 + kc);
      bfr[q][kc] = *(const bf16x8*)(whhf + (frag << 9) + l*8);
    }
  float wv[4], bs[4];
  #pragma unroll
  for (int q=0;q<4;q++){ int g = q*128 + ch; wv[q] = wih[g]; bs[q] = bsum[g]; }
  float bf0 = bfs[0];
  unsigned short* hb[2] = {hA, hB};

  // ---- 15 LSTM steps ----------------------------------------------------
  for (int s = 0; s < NSTEPS; s++){
    if (t == 0 && hasL) wait_flag(&flags[(blk-1)*FSTR], 2+s);
    if (t == 1 && hasR) wait_flag(&flags[(blk+1)*FSTR], 2+s);
    __syncthreads();                      // S0: neighbor h_s published

    // issue halo loads (rows r0-1, r0+2) — land them after the GEMM
    ull hv[4];
    #pragma unroll
    for (int j=0;j<4;j++){
      int chunk = j*512 + t;              // 2048 chunks = 2 halo rows
      int rsel = chunk >> 10, w = chunk & 1023, px = w >> 5, c4 = w & 31;
      bool ok = rsel ? hasR : hasL;
      hv[j] = 0;
      if (ok){
        int grow = r0 + (rsel ? 2 : -1);
        hv[j] = ld_dev((ull*)hb[s&1] + (grow*32 + px)*32 + c4);
      }
    }

    // gates GEMM on own rows (LDS rows 1,2) while halo loads are in flight
    floatx4 acc[4][4];    // [mt][q]
    #pragma unroll
    for (int mt=0;mt<4;mt++)
      #pragma unroll
      for (int q=0;q<4;q++) acc[mt][q] = (floatx4){0.f,0.f,0.f,0.f};
    #pragma unroll
    for (int kc=0; kc<4; kc++){
      bf16x8 a[4];
      #pragma unroll
      for (int mt=0;mt<4;mt++)
        a[mt] = *(const bf16x8*)&sH[SIDX(1+(mt>>1), m16 + (mt&1)*16 + 1, kc*32 + quad*8)];
      #pragma unroll
      for (int q=0; q<4; q++)
        #pragma unroll
        for (int mt=0; mt<4; mt++)
          acc[mt][q] = __builtin_amdgcn_mfma_f32_16x16x32_bf16(a[mt], bfr[q][kc], acc[mt][q], 0,0,0);
    }

    // land halos in LDS rows 0/3 (disjoint from GEMM's rows 1,2)
    #pragma unroll
    for (int j=0;j<4;j++){
      int chunk = j*512 + t;
      int rsel = chunk >> 10, w = chunk & 1023, px = w >> 5, c4 = w & 31;
      bool ok = rsel ? hasR : hasL;
      if (ok) *(ull*)&sH[SIDX(rsel ? 3 : 0, px+1, c4*4)] = hv[j];
    }
    __syncthreads();                      // S1: halos in LDS, A-reads done

    // wf conv: px = t>>3 (0..63), s8 = t&7, rows (px>>5)+ky
    {
      int px = t >> 3, s8 = t & 7;
      int pr = px >> 5, xr = px & 31;
      float a = 0.f;
      #pragma unroll
      for (int ky=0; ky<3; ky++){
        #pragma unroll
        for (int kx=0; kx<3; kx++){
          int base = SIDX(pr + ky, xr + kx, s8*16);
          uint4 h0v = *(const uint4*)&sH[base];
          uint4 h1v = *(const uint4*)&sH[base + 8];
          const float* wp = sWf + (ky*3+kx)*LH + s8*16;
          const unsigned short* hu = (const unsigned short*)&h0v;
          #pragma unroll
          for (int e=0;e<8;e++) a += bf2f(hu[e]) * wp[e];
          hu = (const unsigned short*)&h1v;
          #pragma unroll
          for (int e=0;e<8;e++) a += bf2f(hu[e]) * wp[8+e];
        }
      }
      a += __shfl_xor(a, 1, 64);
      a += __shfl_xor(a, 2, 64);
      a += __shfl_xor(a, 4, 64);
      if (s8 == 0) sInp[px] = a + bf0;
    }
    __syncthreads();                      // S2: sInp ready, row1/2 reads done

    // LSTM pointwise epilogue -> h_{s+1} into LDS rows 1,2
    #pragma unroll
    for (int mt=0; mt<4; mt++){
      #pragma unroll
      for (int r=0; r<4; r++){
        int px = mt*16 + quad*4 + r;
        float iv = sInp[px];
        float pre0 = acc[mt][0][r] + iv*wv[0] + bs[0];
        float pre1 = acc[mt][1][r] + iv*wv[1] + bs[1];
        float pre2 = acc[mt][2][r] + iv*wv[2] + bs[2];
        float pre3 = acc[mt][3][r] + iv*wv[3] + bs[3];
        float ig = sigm(pre0), fg = sigm(pre1), gg = tanh_f(pre2), og = sigm(pre3);
        float cn = fg*c_reg[mt][r] + ig*gg;
        c_reg[mt][r] = cn;
        sH[SIDX(1+(px>>5), (px&31)+1, ch)] = f2bf(og * tanh_f(cn));
      }
    }
    __syncthreads();                      // S3: rows 1,2 hold h_{s+1}

    if (s < NSTEPS-1){
      #pragma unroll
      for (int j=0;j<4;j++){
        int chunk = j*512 + t;
        int r = chunk >> 10, w = chunk & 1023, px = w >> 5, c4 = w & 31;
        st_dev((ull*)hb[(s+1)&1] + (p0 + r*32 + px)*32 + c4,
               *(ull*)&sH[SIDX(1+r, px+1, c4*4)]);
      }
      __syncthreads();                    // S4: vmcnt drained
      if (t == 0) set_flag(&flags[blk*FSTR], 3+s);
    }
  }

  // ---- policy: logits + 4-way softmax from LDS rows 1,2 -----------------
  {
    int px = t >> 3, s8 = t & 7;
    int base = SIDX(1+(px>>5), (px&31)+1, s8*16);
    uint4 h0v = *(const uint4*)&sH[base];
    uint4 h1v = *(const uint4*)&sH[base + 8];
    float la[4] = {0.f,0.f,0.f,0.f};
    const unsigned short* hu = (const unsigned short*)&h0v;
    #pragma unroll
    for (int e=0;e<8;e++){
      int c = s8*16 + e; float hv2 = bf2f(hu[e]);
      const float* w4 = wpol + c*4;
      la[0]+=hv2*w4[0]; la[1]+=hv2*w4[1]; la[2]+=hv2*w4[2]; la[3]+=hv2*w4[3];
    }
    hu = (const unsigned short*)&h1v;
    #pragma unroll
    for (int e=0;e<8;e++){
      int c = s8*16 + 8 + e; float hv2 = bf2f(hu[e]);
      const float* w4 = wpol + c*4;
      la[0]+=hv2*w4[0]; la[1]+=hv2*w4[1]; la[2]+=hv2*w4[2]; la[3]+=hv2*w4[3];
    }
    #pragma unroll
    for (int a=0;a<4;a++){
      la[a] += __shfl_xor(la[a], 1, 64);
      la[a] += __shfl_xor(la[a], 2, 64);
      la[a] += __shfl_xor(la[a], 4, 64);
    }
    if (s8 == 0){
      int y = y0 + (px>>5), x = px & 31;
      float m = fmaxf(fmaxf(la[0],la[1]),fmaxf(la[2],la[3]));
      float e[4]; float sum = 0.f;
      #pragma unroll
      for (int a=0;a<4;a++){ e[a]=__expf(la[a]-m); sum+=e[a]; }
      float inv = 1.f/sum;
      #pragma unroll
      for (int a=0;a<4;a++){
        int o = ((b*4 + a)*MM + y)*MM + x;
        out[o] = la[a];
        out[65536 + o] = e[a]*inv;
      }
    }
  }
}

extern "C" void kernel_launch(void* const* d_in, const int* in_sizes, int n_in,
                              void* d_out, int out_size, void* d_ws, size_t ws_size,
                              hipStream_t stream){
  const float* mp    = (const float*)d_in[0];
  const float* gl    = (const float*)d_in[1];
  const float* W_hid = (const float*)d_in[2];
  const float* b_hid = (const float*)d_in[3];
  const float* W_h0  = (const float*)d_in[4];
  const float* b_h0  = (const float*)d_in[5];
  const float* W_c0  = (const float*)d_in[6];
  const float* b_c0  = (const float*)d_in[7];
  const float* W_f   = (const float*)d_in[8];
  const float* b_f   = (const float*)d_in[9];
  const float* W_ih  = (const float*)d_in[10];
  const float* b_ih  = (const float*)d_in[11];
  const float* W_hh  = (const float*)d_in[12];
  const float* b_hh  = (const float*)d_in[13];
  const float* W_pol = (const float*)d_in[14];
  float* out = (float*)d_out;

  char* ws = (char*)d_ws;
  unsigned short* hA    = (unsigned short*)ws;                          // 4 MB
  unsigned short* hB    = (unsigned short*)(ws + ((size_t) 4<<20));     // 4 MB
  unsigned short* hidb  = (unsigned short*)(ws + ((size_t) 8<<20));     // 4 MB
  unsigned short* whhf  = (unsigned short*)(ws + ((size_t)12<<20));     // 128 KB
  float*          bsum  = (float*)(ws + ((size_t)12<<20) + (128<<10));  // 4 KB
  unsigned short* wc0   = (unsigned short*)(ws + ((size_t)12<<20) + (132<<10)); // 288 KB
  unsigned short* wc1   = (unsigned short*)(ws + ((size_t)12<<20) + (420<<10)); // 288 KB
  int*            flags = (int*)(ws + ((size_t)12<<20) + (708<<10));    // 32 KB

  k_mega<<<NBLK, 512, 0, stream>>>(
      mp, gl, W_hid, b_hid, W_h0, b_h0, W_c0, b_c0, W_f, b_f,
      W_ih, b_ih, W_hh, b_hh, W_pol,
      hA, hB, hidb, wc0, wc1, whhf, bsum, flags, out);
}